// Round 1
// baseline (597.444 us; speedup 1.0000x reference)
//
#include <hip/hip_runtime.h>
#include <math.h>

#define B_ 2
#define H_ 16
#define S_ 2048
#define D_ 72
#define LP 576
#define WEND 1088  // LP + LSEQ

// ---------------- prep: theta + rotary + L2-normalize q,k ----------------
// grid: B*H*S blocks of 128 threads; one (b,h,s) row per block.
__global__ __launch_bounds__(128) void prep_kernel(
    const float* __restrict__ q, const float* __restrict__ k,
    const float* __restrict__ pos, const float* __restrict__ pos_orig,
    const float* __restrict__ time_, const float* __restrict__ freqs,
    const float* __restrict__ t_freqs, const float* __restrict__ scale,
    float* __restrict__ qn, float* __restrict__ kn)
{
    const int r = blockIdx.x;              // r = (b*H + h)*S + s
    const int s = r & (S_ - 1);
    const int h = (r >> 11) & (H_ - 1);    // r / S_ % H_
    const int b = r >> 15;                 // r / (H_*S_)
    const int t = threadIdx.x;

    __shared__ float redq[128], redk[128];

    float qv = 0.f, kv = 0.f;
    const long base = (long)r * D_;
    if (t < 72) {
        if (t < 60) {
            const int jj = (t < 30) ? t : t - 30;
            const int g = jj / 6, i = jj - g * 6;
            const int p2 = (b * S_ + s) * 2;
            float bv, f;
            if (g == 0)      { bv = pos_orig[p2 + 1] * 2.f - 1.f; f = freqs[96 + h * 6 + i]; }
            else if (g == 1) { bv = pos[p2 + 1]      * 2.f - 1.f; f = freqs[96 + h * 6 + i]; }
            else if (g == 2) { bv = pos_orig[p2 + 0] * 2.f - 1.f; f = freqs[h * 6 + i]; }
            else if (g == 3) { bv = pos[p2 + 0]      * 2.f - 1.f; f = freqs[h * 6 + i]; }
            else             { bv = time_[b * S_ + s];            f = t_freqs[h * 6 + i]; }
            const float th = bv * f;
            float c, sn;
            __sincosf(th, &sn, &c);
            const float x1q = q[base + jj], x2q = q[base + jj + 30];
            const float x1k = k[base + jj], x2k = k[base + jj + 30];
            if (t < 30) { qv = x1q * c - x2q * sn; kv = x1k * c - x2k * sn; }
            else        { qv = x2q * c + x1q * sn; kv = x2k * c + x1k * sn; }
        } else {
            qv = q[base + t]; kv = k[base + t];
        }
    }
    redq[t] = qv * qv;
    redk[t] = kv * kv;
    __syncthreads();
    for (int off = 64; off > 0; off >>= 1) {
        if (t < off) { redq[t] += redq[t + off]; redk[t] += redk[t + off]; }
        __syncthreads();
    }
    const float ss = sqrtf(scale[h]);
    const float fq = ss * rsqrtf(redq[0] + 1e-6f);
    const float fk = ss * rsqrtf(redk[0] + 1e-6f);
    if (t < 72) {
        qn[base + t] = qv * fq;
        kn[base + t] = kv * fk;
    }
}

// ---------------- attention ----------------
// grid: (S/32, B*H), 256 threads. One 32-row q-tile per block.
// Scores bounded in [-1.5,1.5] -> no running-max softmax needed.
__global__ __launch_bounds__(256) void attn_kernel(
    const float* __restrict__ qn, const float* __restrict__ kn,
    const float* __restrict__ v, float* __restrict__ out)
{
    const int q0 = blockIdx.x * 32;
    const int bh = blockIdx.y;
    const int t  = threadIdx.x;

    if (q0 < LP) {  // fully-masked rows -> zeros
        float4* o4 = (float4*)(out + (long)(bh * S_ + q0) * D_);
        for (int i = t; i < 32 * 18; i += 256) o4[i] = make_float4(0.f, 0.f, 0.f, 0.f);
        return;
    }

    __shared__ float qs[32 * 72];
    __shared__ float ks[64 * 76];   // pad 72->76 (bank spread)
    __shared__ float vs[64 * 76];
    __shared__ float ps[32 * 68];   // pad 64->68

    // load Q tile (rows contiguous)
    {
        const float4* g4 = (const float4*)(qn + (long)(bh * S_ + q0) * D_);
        float4* l4 = (float4*)qs;
        for (int i = t; i < 576; i += 256) l4[i] = g4[i];
    }

    const bool causal = (q0 < WEND);
    const int ntiles = causal ? ((q0 + 31) >> 6) + 1 : (WEND >> 6);

    const int kq = t & 15, qq = t >> 4;   // score-phase mapping: 2q x 4k per thread
    const int dq = t & 7,  qr = t >> 3;   // PV mapping: row qr, dims dq*8..+7 and 64+dq
    const int q_abs_pv = q0 + qr;

    float4 oA = make_float4(0.f,0.f,0.f,0.f), oB = make_float4(0.f,0.f,0.f,0.f);
    float oE = 0.f, den = 0.f;

    for (int kt = 0; kt < ntiles; ++kt) {
        const int k0 = kt * 64;
        __syncthreads();  // prev PV done with ks/vs/ps
        {
            const float4* gk = (const float4*)(kn + (long)(bh * S_ + k0) * D_);
            const float4* gv = (const float4*)(v  + (long)(bh * S_ + k0) * D_);
            float4* lk = (float4*)ks;
            float4* lv = (float4*)vs;
            for (int i = t; i < 64 * 18; i += 256) {
                const int row = i / 18, col = i - row * 18;
                lk[row * 19 + col] = gk[i];
                lv[row * 19 + col] = gv[i];
            }
        }
        __syncthreads();

        // ---- scores: rows {2qq,2qq+1} x keys {kq+16j} ----
        float acc[2][4] = {};
        const float4* q4 = (const float4*)qs;
        const float4* k4 = (const float4*)ks;
        #pragma unroll 6
        for (int dd = 0; dd < 18; ++dd) {
            const float4 qa = q4[(qq * 2)     * 18 + dd];
            const float4 qb = q4[(qq * 2 + 1) * 18 + dd];
            #pragma unroll
            for (int j = 0; j < 4; ++j) {
                const float4 kk = k4[(kq + 16 * j) * 19 + dd];
                acc[0][j] += qa.x * kk.x + qa.y * kk.y + qa.z * kk.z + qa.w * kk.w;
                acc[1][j] += qb.x * kk.x + qb.y * kk.y + qb.z * kk.z + qb.w * kk.w;
            }
        }
        #pragma unroll
        for (int i = 0; i < 2; ++i) {
            const int q_abs = q0 + qq * 2 + i;
            #pragma unroll
            for (int j = 0; j < 4; ++j) {
                const int k_abs = k0 + kq + 16 * j;
                const float p = (!causal || k_abs <= q_abs) ? __expf(acc[i][j]) : 0.f;
                ps[(qq * 2 + i) * 68 + kq + 16 * j] = p;
            }
        }
        __syncthreads();

        // ---- PV: row qr, 17 dims per thread ----
        const float4* v4 = (const float4*)vs;
        #pragma unroll 4
        for (int kk = 0; kk < 64; ++kk) {
            const float p = ps[qr * 68 + kk];
            den += p;
            const float4 va = v4[kk * 19 + dq * 2];
            const float4 vb = v4[kk * 19 + dq * 2 + 1];
            oA.x += p * va.x; oA.y += p * va.y; oA.z += p * va.z; oA.w += p * va.w;
            oB.x += p * vb.x; oB.y += p * vb.y; oB.z += p * vb.z; oB.w += p * vb.w;
            oE += p * vs[kk * 76 + 64 + dq];
        }
    }

    // ---- window rows: self-key k = q_abs ----
    if (!causal) {
        const long kbase = (long)(bh * S_ + q_abs_pv) * D_;
        float part = 0.f;
        #pragma unroll
        for (int j = 0; j < 8; ++j) part += qs[qr * 72 + dq * 8 + j] * kn[kbase + dq * 8 + j];
        part += qs[qr * 72 + 64 + dq] * kn[kbase + 64 + dq];
        part += __shfl_xor(part, 1);
        part += __shfl_xor(part, 2);
        part += __shfl_xor(part, 4);
        const float p = __expf(part);
        den += p;
        const float4* gv4 = (const float4*)(v + kbase);
        const float4 va = gv4[dq * 2], vb = gv4[dq * 2 + 1];
        oA.x += p * va.x; oA.y += p * va.y; oA.z += p * va.z; oA.w += p * va.w;
        oB.x += p * vb.x; oB.y += p * vb.y; oB.z += p * vb.z; oB.w += p * vb.w;
        oE += p * v[kbase + 64 + dq];
    }

    const float inv = 1.f / den;
    float* orow = out + (long)(bh * S_ + q_abs_pv) * D_;
    float4* o4 = (float4*)orow;
    float4 ra, rb;
    ra.x = oA.x * inv; ra.y = oA.y * inv; ra.z = oA.z * inv; ra.w = oA.w * inv;
    rb.x = oB.x * inv; rb.y = oB.y * inv; rb.z = oB.z * inv; rb.w = oB.w * inv;
    o4[dq * 2] = ra;
    o4[dq * 2 + 1] = rb;
    orow[64 + dq] = oE * inv;
}

extern "C" void kernel_launch(void* const* d_in, const int* in_sizes, int n_in,
                              void* d_out, int out_size, void* d_ws, size_t ws_size,
                              hipStream_t stream) {
    const float* q        = (const float*)d_in[0];
    const float* k        = (const float*)d_in[1];
    const float* v        = (const float*)d_in[2];
    const float* pos      = (const float*)d_in[3];
    const float* pos_orig = (const float*)d_in[4];
    const float* time_    = (const float*)d_in[5];
    const float* freqs    = (const float*)d_in[6];
    const float* t_freqs  = (const float*)d_in[7];
    const float* scale    = (const float*)d_in[8];
    float* out = (float*)d_out;

    float* qn = (float*)d_ws;
    float* kn = qn + (size_t)B_ * H_ * S_ * D_;

    prep_kernel<<<dim3(B_ * H_ * S_), dim3(128), 0, stream>>>(
        q, k, pos, pos_orig, time_, freqs, t_freqs, scale, qn, kn);
    attn_kernel<<<dim3(S_ / 32, B_ * H_), dim3(256), 0, stream>>>(qn, kn, v, out);
}

// Round 3
// 251.425 us; speedup vs baseline: 2.3762x; 2.3762x over previous
//
#include <hip/hip_runtime.h>
#include <math.h>

#define B_ 2
#define H_ 16
#define S_ 2048
#define D_ 72
#define LP 576
#define WEND 1088
#define DP 96        // padded D for qn/kn (3 chunks of 32)
#define DV 80        // padded dims for Vt (5 tiles of 16)
#define KS_STRIDE 52 // words per K LDS row (104 bf16)
#define VT_STRIDE 20 // words per Vt LDS row (40 bf16)
#define PS_STRIDE 20 // words per P LDS row (40 bf16)
#define VT_BASE (32 * KS_STRIDE)            // 1664
#define PS_BASE (VT_BASE + DV * VT_STRIDE)  // 3264

typedef __bf16 bf16x8 __attribute__((ext_vector_type(8)));
typedef float f32x4 __attribute__((ext_vector_type(4)));

static __device__ __forceinline__ unsigned pack2bf(float a, float b) {
    __bf16 x = (__bf16)a, y = (__bf16)b;
    unsigned short ux = __builtin_bit_cast(unsigned short, x);
    unsigned short uy = __builtin_bit_cast(unsigned short, y);
    return (unsigned)ux | ((unsigned)uy << 16);
}

static __device__ __forceinline__ f32x4 mfma16(bf16x8 a, bf16x8 b, f32x4 c) {
    return __builtin_amdgcn_mfma_f32_16x16x32_bf16(a, b, c, 0, 0, 0);
}

// ---------- prep: rotary + normalize -> bf16 qn/kn padded to 96 ----------
__global__ __launch_bounds__(256) void prep_kernel(
    const float* __restrict__ q, const float* __restrict__ k,
    const float* __restrict__ pos, const float* __restrict__ pos_orig,
    const float* __restrict__ time_, const float* __restrict__ freqs,
    const float* __restrict__ t_freqs, const float* __restrict__ scale,
    unsigned* __restrict__ qn, unsigned* __restrict__ kn)
{
    const int row = blockIdx.x * 4 + (threadIdx.x >> 6);
    const int t = threadIdx.x & 63;
    const int s = row & (S_ - 1);
    const int h = (row >> 11) & (H_ - 1);
    const int b = row >> 15;
    const long base = (long)row * D_;

    float q0v = 0.f, q1v = 0.f, k0v = 0.f, k1v = 0.f;
    if (t < 30) {
        const bool x1role = (t < 15);
        const int jj0 = x1role ? 2 * t : 2 * t - 30;
        const float2 qlo = *(const float2*)(q + base + jj0);
        const float2 qhi = *(const float2*)(q + base + jj0 + 30);
        const float2 klo = *(const float2*)(k + base + jj0);
        const float2 khi = *(const float2*)(k + base + jj0 + 30);
        const int p2 = (b * S_ + s) * 2;
        float c0, s0, c1, s1;
        {
            const int g = jj0 / 6, i = jj0 - g * 6;
            float bv, f;
            if (g == 0)      { bv = pos_orig[p2 + 1] * 2.f - 1.f; f = freqs[96 + h * 6 + i]; }
            else if (g == 1) { bv = pos[p2 + 1]      * 2.f - 1.f; f = freqs[96 + h * 6 + i]; }
            else if (g == 2) { bv = pos_orig[p2 + 0] * 2.f - 1.f; f = freqs[h * 6 + i]; }
            else if (g == 3) { bv = pos[p2 + 0]      * 2.f - 1.f; f = freqs[h * 6 + i]; }
            else             { bv = time_[b * S_ + s];            f = t_freqs[h * 6 + i]; }
            __sincosf(bv * f, &s0, &c0);
        }
        {
            const int jj1 = jj0 + 1;
            const int g = jj1 / 6, i = jj1 - g * 6;
            float bv, f;
            if (g == 0)      { bv = pos_orig[p2 + 1] * 2.f - 1.f; f = freqs[96 + h * 6 + i]; }
            else if (g == 1) { bv = pos[p2 + 1]      * 2.f - 1.f; f = freqs[96 + h * 6 + i]; }
            else if (g == 2) { bv = pos_orig[p2 + 0] * 2.f - 1.f; f = freqs[h * 6 + i]; }
            else if (g == 3) { bv = pos[p2 + 0]      * 2.f - 1.f; f = freqs[h * 6 + i]; }
            else             { bv = time_[b * S_ + s];            f = t_freqs[h * 6 + i]; }
            __sincosf(bv * f, &s1, &c1);
        }
        if (x1role) {
            q0v = qlo.x * c0 - qhi.x * s0;  q1v = qlo.y * c1 - qhi.y * s1;
            k0v = klo.x * c0 - khi.x * s0;  k1v = klo.y * c1 - khi.y * s1;
        } else {
            q0v = qhi.x * c0 + qlo.x * s0;  q1v = qhi.y * c1 + qlo.y * s1;
            k0v = khi.x * c0 + klo.x * s0;  k1v = khi.y * c1 + klo.y * s1;
        }
    } else if (t < 36) {
        const float2 qv = *(const float2*)(q + base + 2 * t);
        const float2 kv = *(const float2*)(k + base + 2 * t);
        q0v = qv.x; q1v = qv.y; k0v = kv.x; k1v = kv.y;
    }
    float sq = q0v * q0v + q1v * q1v;
    float sk = k0v * k0v + k1v * k1v;
    #pragma unroll
    for (int m = 1; m < 64; m <<= 1) { sq += __shfl_xor(sq, m); sk += __shfl_xor(sk, m); }
    const float ss = sqrtf(scale[h]);
    const float fq = ss * rsqrtf(sq + 1e-6f);
    const float fk = ss * rsqrtf(sk + 1e-6f);
    const long obase = (long)row * 48;
    if (t < 36) {
        qn[obase + t] = pack2bf(q0v * fq, q1v * fq);
        kn[obase + t] = pack2bf(k0v * fk, k1v * fk);
    } else if (t < 48) {
        qn[obase + t] = 0u;
        kn[obase + t] = 0u;
    }
}

// ---------- vtrans: V fp32 [bh][s][72] -> bf16 Vt [bh][80][s] ----------
__global__ __launch_bounds__(256) void vtrans_kernel(
    const float* __restrict__ v, unsigned short* __restrict__ vt)
{
    const int s0 = blockIdx.x * 64;
    const int bh = blockIdx.y;
    const int t = threadIdx.x;
    __shared__ float tile[64 * 77];
    for (int i = t; i < 1152; i += 256) {
        const int r = i / 18, c = i - r * 18;
        const float4 g = ((const float4*)v)[((long)(bh * S_ + s0 + r) * 18) + c];
        float* d = &tile[r * 77 + c * 4];
        d[0] = g.x; d[1] = g.y; d[2] = g.z; d[3] = g.w;
    }
    __syncthreads();
    for (int i = t; i < 1280; i += 256) {
        const int dd = i >> 4, s4 = i & 15;
        float f0 = 0.f, f1 = 0.f, f2 = 0.f, f3 = 0.f;
        if (dd < D_) {
            f0 = tile[(s4 * 4 + 0) * 77 + dd];
            f1 = tile[(s4 * 4 + 1) * 77 + dd];
            f2 = tile[(s4 * 4 + 2) * 77 + dd];
            f3 = tile[(s4 * 4 + 3) * 77 + dd];
        }
        uint2 o; o.x = pack2bf(f0, f1); o.y = pack2bf(f2, f3);
        ((uint2*)vt)[((((long)bh * DV + dd) << 11) + s0 + s4 * 4) >> 2] = o;
    }
}

// ---------- zero out rows q < LP ----------
__global__ __launch_bounds__(256) void zero_kernel(float4* __restrict__ out) {
    const int t0 = blockIdx.x * 1024 + threadIdx.x;
    #pragma unroll
    for (int j = 0; j < 4; ++j) {
        const int i = t0 + j * 256;
        const int bh = i / 10368;            // 576*72/4 f4 per bh
        const int rem = i - bh * 10368;
        out[(long)bh * 36864 + rem] = make_float4(0.f, 0.f, 0.f, 0.f);
    }
}

// ---------- attention: 2 waves x 32 q-rows, 32-key tiles, MFMA ----------
__global__ __launch_bounds__(128) void attn_kernel(
    const unsigned short* __restrict__ qn, const unsigned short* __restrict__ kn,
    const unsigned short* __restrict__ vt, float* __restrict__ out)
{
    __shared__ __align__(16) unsigned lds[PS_BASE + 2 * 640];
    const int bh = blockIdx.y;
    const int q0 = LP + blockIdx.x * 64;
    const int tid = threadIdx.x;
    const int w = tid >> 6, lane = tid & 63;
    const int quad = lane >> 4, l16 = lane & 15;
    const int q0w = q0 + w * 32;
    const bool causal = (q0 < WEND);
    const int ntiles = causal ? ((q0 + 63) >> 5) + 1 : (WEND >> 5);

    const unsigned short* qn_b = qn + (((long)bh) << 11) * DP;
    const unsigned short* kn_b = kn + (((long)bh) << 11) * DP;
    const unsigned short* vt_b = vt + (long)bh * DV * S_;

    bf16x8 qf[2][3];
    #pragma unroll
    for (int m = 0; m < 2; ++m)
        #pragma unroll
        for (int c = 0; c < 3; ++c)
            qf[m][c] = *(const bf16x8*)(qn_b + (long)(q0w + m * 16 + l16) * DP + c * 32 + quad * 8);

    f32x4 o[2][5];
    float den[2][4];
    #pragma unroll
    for (int m = 0; m < 2; ++m) {
        #pragma unroll
        for (int dt = 0; dt < 5; ++dt) { o[m][dt][0]=0.f; o[m][dt][1]=0.f; o[m][dt][2]=0.f; o[m][dt][3]=0.f; }
        #pragma unroll
        for (int r = 0; r < 4; ++r) den[m][r] = 0.f;
    }

    unsigned* Ps = lds + PS_BASE + w * 640;

    for (int kt = 0; kt < ntiles; ++kt) {
        const int k0 = kt * 32;
        for (int i = tid; i < 704; i += 128) {
            if (i < 384) {
                const int r = i / 12, seg = i - r * 12;
                const int key = k0 + 2 * (r & 15) + (r >> 4);   // even/odd interleave
                *(uint4*)(lds + r * KS_STRIDE + seg * 4) =
                    *(const uint4*)(kn_b + (long)key * DP + seg * 8);
            } else {
                const int j2 = i - 384;
                const int r = j2 >> 2, seg = j2 & 3;
                *(uint4*)(lds + VT_BASE + r * VT_STRIDE + seg * 4) =
                    *(const uint4*)(vt_b + (((long)r) << 11) + k0 + seg * 8);
            }
        }
        __syncthreads();
        if (!causal || k0 <= q0w + 31) {
            f32x4 acc[2][2];
            #pragma unroll
            for (int m = 0; m < 2; ++m)
                #pragma unroll
                for (int n = 0; n < 2; ++n) { acc[m][n][0]=0.f; acc[m][n][1]=0.f; acc[m][n][2]=0.f; acc[m][n][3]=0.f; }
            #pragma unroll
            for (int c = 0; c < 3; ++c) {
                const bf16x8 kf0 = *(const bf16x8*)(lds + (l16)      * KS_STRIDE + c * 16 + quad * 4);
                const bf16x8 kf1 = *(const bf16x8*)(lds + (16 + l16) * KS_STRIDE + c * 16 + quad * 4);
                acc[0][0] = mfma16(qf[0][c], kf0, acc[0][0]);
                acc[0][1] = mfma16(qf[0][c], kf1, acc[0][1]);
                acc[1][0] = mfma16(qf[1][c], kf0, acc[1][0]);
                acc[1][1] = mfma16(qf[1][c], kf1, acc[1][1]);
            }
            const int kb = k0 + 2 * l16;
            #pragma unroll
            for (int m = 0; m < 2; ++m) {
                #pragma unroll
                for (int r = 0; r < 4; ++r) {
                    const int qa = q0w + m * 16 + quad * 4 + r;
                    float p0 = acc[m][0][r], p1 = acc[m][1][r];
                    p0 = (!causal || kb     <= qa) ? __expf(p0) : 0.f;
                    p1 = (!causal || kb + 1 <= qa) ? __expf(p1) : 0.f;
                    const __bf16 pb0 = (__bf16)p0, pb1 = (__bf16)p1;
                    den[m][r] += (float)pb0 + (float)pb1;   // consistent with PV numerator
                    unsigned pk = (unsigned)__builtin_bit_cast(unsigned short, pb0) |
                                  ((unsigned)__builtin_bit_cast(unsigned short, pb1) << 16);
                    Ps[(m * 16 + quad * 4 + r) * PS_STRIDE + l16] = pk;
                }
            }
            __builtin_amdgcn_sched_barrier(0);   // P LDS write -> read (same wave, HW in-order)
            bf16x8 pa[2];
            pa[0] = *(const bf16x8*)(Ps + (l16)      * PS_STRIDE + quad * 4);
            pa[1] = *(const bf16x8*)(Ps + (16 + l16) * PS_STRIDE + quad * 4);
            #pragma unroll
            for (int dt = 0; dt < 5; ++dt) {
                const bf16x8 vf = *(const bf16x8*)(lds + VT_BASE + (dt * 16 + l16) * VT_STRIDE + quad * 4);
                o[0][dt] = mfma16(pa[0], vf, o[0][dt]);
                o[1][dt] = mfma16(pa[1], vf, o[1][dt]);
            }
        }
        __syncthreads();
    }

    #pragma unroll
    for (int m = 0; m < 2; ++m)
        #pragma unroll
        for (int r = 0; r < 4; ++r)
            #pragma unroll
            for (int x = 1; x < 16; x <<= 1) den[m][r] += __shfl_xor(den[m][r], x);

    if (!causal) {  // diagonal self-key k == q
        float* PsF = (float*)(lds + PS_BASE + w * 640);
        #pragma unroll
        for (int m = 0; m < 2; ++m) {
            float sp = 0.f;
            #pragma unroll
            for (int c = 0; c < 3; ++c) {
                const bf16x8 kd = *(const bf16x8*)(kn_b + (long)(q0w + m * 16 + l16) * DP + c * 32 + quad * 8);
                #pragma unroll
                for (int j = 0; j < 8; ++j) sp += (float)qf[m][c][j] * (float)kd[j];
            }
            sp += __shfl_xor(sp, 16);
            sp += __shfl_xor(sp, 32);
            if (quad == 0) PsF[m * 16 + l16] = __expf(sp);
        }
        __builtin_amdgcn_sched_barrier(0);
        #pragma unroll
        for (int m = 0; m < 2; ++m)
            #pragma unroll
            for (int r = 0; r < 4; ++r) {
                const float pd = PsF[m * 16 + quad * 4 + r];
                den[m][r] += pd;
                const int qa = q0w + m * 16 + quad * 4 + r;
                #pragma unroll
                for (int dt = 0; dt < 5; ++dt) {
                    const unsigned short uv = vt_b[(((long)(dt * 16 + l16)) << 11) + qa];
                    o[m][dt][r] += pd * (float)__builtin_bit_cast(__bf16, uv);
                }
            }
    }

    #pragma unroll
    for (int m = 0; m < 2; ++m)
        #pragma unroll
        for (int r = 0; r < 4; ++r) {
            const float inv = 1.f / den[m][r];
            const int qa = q0w + m * 16 + quad * 4 + r;
            float* orow = out + ((long)(bh * S_ + qa)) * D_;
            #pragma unroll
            for (int dt = 0; dt < 5; ++dt) {
                const int dim = dt * 16 + l16;
                if (dim < D_) orow[dim] = o[m][dt][r] * inv;
            }
        }
}

extern "C" void kernel_launch(void* const* d_in, const int* in_sizes, int n_in,
                              void* d_out, int out_size, void* d_ws, size_t ws_size,
                              hipStream_t stream) {
    const float* q        = (const float*)d_in[0];
    const float* k        = (const float*)d_in[1];
    const float* v        = (const float*)d_in[2];
    const float* pos      = (const float*)d_in[3];
    const float* pos_orig = (const float*)d_in[4];
    const float* time_    = (const float*)d_in[5];
    const float* freqs    = (const float*)d_in[6];
    const float* t_freqs  = (const float*)d_in[7];
    const float* scale    = (const float*)d_in[8];
    float* out = (float*)d_out;

    unsigned* qn = (unsigned*)d_ws;
    unsigned* kn = qn + (size_t)B_ * H_ * S_ * 48;
    unsigned short* vt = (unsigned short*)(kn + (size_t)B_ * H_ * S_ * 48);

    prep_kernel<<<dim3(B_ * H_ * S_ / 4), dim3(256), 0, stream>>>(
        q, k, pos, pos_orig, time_, freqs, t_freqs, scale, qn, kn);
    vtrans_kernel<<<dim3(S_ / 64, B_ * H_), dim3(256), 0, stream>>>(v, vt);
    zero_kernel<<<dim3(324), dim3(256), 0, stream>>>((float4*)out);
    attn_kernel<<<dim3((S_ - LP) / 64, B_ * H_), dim3(128), 0, stream>>>(
        (const unsigned short*)qn, (const unsigned short*)kn, vt, out);
}